// Round 2
// baseline (1389.966 us; speedup 1.0000x reference)
//
#include <hip/hip_runtime.h>
#include <cstdint>
#include <cstddef>
#include <math.h>

// Problem constants (match reference: B,C,N,K = 16,64,2048,20)
#define BB 16
#define CC 64
#define NN 2048
#define KK 20
#define K2 14   // ceil(20*2/3)
#define TQ 4    // queries per block in knn kernel

// ---------------------------------------------------------------------------
// Kernel A: xx[b*N+n] = sum_c x[b,c,n]^2  (fp64 accumulate, fp64 store)
// ---------------------------------------------------------------------------
__global__ __launch_bounds__(256) void xx_kernel(const float* __restrict__ x,
                                                 double* __restrict__ xx) {
    int p = blockIdx.x * 256 + threadIdx.x;        // 0 .. B*N-1
    int b = p >> 11;
    int n = p & (NN - 1);
    const float* xb = x + (size_t)b * CC * NN;
    double s = 0.0;
#pragma unroll
    for (int c = 0; c < CC; ++c) {
        double v = (double)xb[c * NN + n];
        s += v * v;
    }
    xx[p] = s;
}

// ---------------------------------------------------------------------------
// Kernel B: per query point, compute pd row (fp64, in LDS) and select top-20
// (lax.top_k semantics: descending values, ties -> lower index first).
// Block = 256 threads, handles TQ=4 consecutive queries of one batch.
// fp64 distances ensure the ordering matches the (fp64) numpy reference
// except true ties, which are measure-zero for Gaussian inputs.
// ---------------------------------------------------------------------------
__global__ __launch_bounds__(256) void knn_kernel(const float* __restrict__ x,
                                                  const double* __restrict__ xx,
                                                  int* __restrict__ idx_ws,
                                                  float* __restrict__ idx_out) {
    __shared__ double s_pd[TQ][NN];                // 64 KiB
    __shared__ double s_q[CC][TQ];                 // 2 KiB

    int tid = threadIdx.x;
    int b = blockIdx.x / (NN / TQ);
    int n0 = (blockIdx.x % (NN / TQ)) * TQ;
    const float* xb = x + (size_t)b * CC * NN;

    // stage the 4 query vectors (channel-major)
    {
        int c = tid >> 2, q = tid & 3;
        s_q[c][q] = (double)xb[c * NN + n0 + q];
    }
    __syncthreads();

    double xxn[TQ];
#pragma unroll
    for (int q = 0; q < TQ; ++q) xxn[q] = xx[b * NN + n0 + q];

    // ---- distance fill: each thread owns 4 consecutive m, 2 groups ----
    for (int g = 0; g < NN / (256 * 4); ++g) {
        int m = g * 1024 + tid * 4;
        double acc[4][TQ];
#pragma unroll
        for (int i = 0; i < 4; ++i)
#pragma unroll
            for (int q = 0; q < TQ; ++q) acc[i][q] = 0.0;

        for (int c = 0; c < CC; ++c) {
            float4 xv = *(const float4*)(xb + c * NN + m);
            double xs[4] = {(double)xv.x, (double)xv.y, (double)xv.z, (double)xv.w};
            double qs[4];
#pragma unroll
            for (int q = 0; q < TQ; ++q) qs[q] = s_q[c][q];
#pragma unroll
            for (int i = 0; i < 4; ++i)
#pragma unroll
                for (int q = 0; q < TQ; ++q) acc[i][q] += qs[q] * xs[i];
        }
#pragma unroll
        for (int i = 0; i < 4; ++i) {
            double xm = xx[b * NN + m + i];
#pragma unroll
            for (int q = 0; q < TQ; ++q)
                s_pd[q][m + i] = (2.0 * acc[i][q] - xxn[q]) - xm;
        }
    }
    __syncthreads();

    // ---- selection: wave per query ----
    int q = tid >> 6;
    int lane = tid & 63;
    double* pd = s_pd[q];
    int n_glob = n0 + q;
    size_t obase = ((size_t)b * NN + n_glob) * KK;

    for (int t = 0; t < KK; ++t) {
        double best = -INFINITY;
        int bi = NN;
#pragma unroll
        for (int r = 0; r < NN / 64; ++r) {
            int m = lane + r * 64;
            double v = pd[m];
            if (v > best) { best = v; bi = m; }   // strict > keeps lowest m
        }
#pragma unroll
        for (int off = 32; off; off >>= 1) {
            double ov = __shfl_down(best, off);
            int oi = __shfl_down(bi, off);
            if (ov > best || (ov == best && oi < bi)) { best = ov; bi = oi; }
        }
        bi = __shfl(bi, 0);
        if (lane == 0) {
            idx_ws[obase + t] = bi;
            idx_out[obase + t] = (float)(bi + b * NN);   // idx_flat encoding
            pd[bi] = -INFINITY;
        }
        __syncthreads();   // publish invalidation (uniform trip count)
    }
}

// ---------------------------------------------------------------------------
// Kernel C: x1[b,n,c] = mean of top-14 of the 20 gathered neighbor values.
// Block = 256 threads = 4 points x 64 channels.
// ---------------------------------------------------------------------------
__global__ __launch_bounds__(256) void x1_kernel(const float* __restrict__ x,
                                                 const int* __restrict__ idx_ws,
                                                 float* __restrict__ x1) {
    __shared__ int s_idx[4][KK];
    int tid = threadIdx.x;
    int p0 = blockIdx.x * 4;                       // flat point index base
    if (tid < 4 * KK) s_idx[tid / KK][tid % KK] = idx_ws[(size_t)p0 * KK + tid];
    __syncthreads();

    int pl = tid >> 6, c = tid & 63;
    int p = p0 + pl;
    int b = p >> 11;
    const float* xrow = x + (size_t)b * CC * NN + (size_t)c * NN;

    float vals[KK];
#pragma unroll
    for (int j = 0; j < KK; ++j) vals[j] = xrow[s_idx[pl][j]];

    float sum = 0.f;
    for (int t = 0; t < K2; ++t) {
        float best = -INFINITY;
        int bj = 0;
#pragma unroll
        for (int j = 0; j < KK; ++j)
            if (vals[j] > best) { best = vals[j]; bj = j; }
        sum += best;
        vals[bj] = -INFINITY;
    }
    x1[(size_t)p * CC + c] = sum / (float)K2;
}

// ---------------------------------------------------------------------------
// Kernel D: feature[b,ch,n,j]:
//   ch <  64: x1[b, idx[b,n,j], ch] - x[b,ch,n]
//   ch >= 64: x[b,ch-64,n]
// Block per (b,ch); coalesced writes over the contiguous N*K tail.
// ---------------------------------------------------------------------------
__global__ __launch_bounds__(256) void feat_kernel(const float* __restrict__ x,
                                                   const float* __restrict__ x1,
                                                   const int* __restrict__ idx_ws,
                                                   float* __restrict__ out) {
    int bc = blockIdx.x;
    int b = bc >> 7, ch = bc & 127;
    const float* xb = x + (size_t)b * CC * NN;
    float* o = out + (size_t)bc * NN * KK;
    const int* idxb = idx_ws + (size_t)b * NN * KK;

    if (ch < CC) {
        const float* x1b = x1 + (size_t)b * NN * CC + ch;
        const float* xr = xb + ch * NN;
        for (int e = threadIdx.x; e < NN * KK; e += 256) {
            int n = e / KK;
            int id = idxb[e];
            o[e] = x1b[(size_t)id * CC] - xr[n];
        }
    } else {
        const float* xr = xb + (ch - CC) * NN;
        for (int e = threadIdx.x; e < NN * KK; e += 256) {
            o[e] = xr[e / KK];
        }
    }
}

// ---------------------------------------------------------------------------
extern "C" void kernel_launch(void* const* d_in, const int* in_sizes, int n_in,
                              void* d_out, int out_size, void* d_ws, size_t ws_size,
                              hipStream_t stream) {
    const float* x = (const float*)d_in[0];   // (B, C, N) fp32
    // d_in[1] = k (scalar, fixed 20), d_in[2] = local_idx (unused)
    float* out = (float*)d_out;

    // workspace layout
    char* ws = (char*)d_ws;
    double* xx = (double*)ws;                                      // B*N doubles
    int* idx_ws = (int*)(ws + (size_t)BB * NN * sizeof(double));   // B*N*K ints
    float* x1 = (float*)(ws + (size_t)BB * NN * sizeof(double)
                            + (size_t)BB * NN * KK * sizeof(int)); // B*N*C floats

    float* idx_out = out + (size_t)BB * 2 * CC * NN * KK;          // idx_flat tail

    xx_kernel<<<(BB * NN) / 256, 256, 0, stream>>>(x, xx);
    knn_kernel<<<BB * (NN / TQ), 256, 0, stream>>>(x, xx, idx_ws, idx_out);
    x1_kernel<<<(BB * NN) / 4, 256, 0, stream>>>(x, idx_ws, x1);
    feat_kernel<<<BB * 2 * CC, 256, 0, stream>>>(x, x1, idx_ws, out);
}

// Round 3
// 911.355 us; speedup vs baseline: 1.5252x; 1.5252x over previous
//
#include <hip/hip_runtime.h>
#include <cstdint>
#include <cstddef>
#include <math.h>

// Problem constants (match reference: B,C,N,K = 16,64,2048,20)
#define BB 16
#define CC 64
#define NN 2048
#define KK 20
#define K2 14   // ceil(20*2/3)
#define TQ 4    // queries per block in knn kernel
#define NC 26   // fp32 candidate count (margin over K=20 for fp32->fp64 rank safety)

// ---------------------------------------------------------------------------
// prep: xt[b][n][c] = x[b][c][n]  (fp32, 256B rows), plus norms in fp64+fp32.
// Block = 256 thr, tile 64c x 64n via LDS.
// ---------------------------------------------------------------------------
__global__ __launch_bounds__(256) void prep_kernel(const float* __restrict__ x,
                                                   float* __restrict__ xt,
                                                   float* __restrict__ xxf,
                                                   double* __restrict__ xxd) {
    __shared__ float s_t[64][65];
    int b = blockIdx.x >> 5;
    int n0 = (blockIdx.x & 31) * 64;
    const float* xb = x + (size_t)b * CC * NN;
    int tid = threadIdx.x;
    int cq = tid >> 6;      // 0..3
    int nl = tid & 63;

#pragma unroll
    for (int r = 0; r < 16; ++r) {
        int c = r * 4 + cq;
        s_t[c][nl] = xb[c * NN + n0 + nl];          // coalesced over n
    }
    __syncthreads();

#pragma unroll
    for (int r = 0; r < 16; ++r) {
        int n = r * 4 + cq;
        xt[((size_t)b * NN + n0 + n) * CC + nl] = s_t[nl][n];   // coalesced over c
    }

    if (tid < 64) {
        double s = 0.0;
#pragma unroll
        for (int c = 0; c < CC; ++c) {
            double v = (double)s_t[c][tid];
            s += v * v;
        }
        xxd[b * NN + n0 + tid] = s;
        xxf[b * NN + n0 + tid] = (float)s;
    }
}

// ---------------------------------------------------------------------------
// knn: fp32 distance fill (LDS) -> fp32 top-26 select -> fp64 refine of the
// 26 candidates -> bitonic sort (val desc, idx asc) -> top-20 out.
// Block = 256 thr = 4 waves; wave per query.
// ---------------------------------------------------------------------------
__global__ __launch_bounds__(256) void knn_kernel(const float* __restrict__ x,
                                                  const float* __restrict__ xt,
                                                  const float* __restrict__ xxf,
                                                  const double* __restrict__ xxd,
                                                  int* __restrict__ idx_ws,
                                                  float* __restrict__ idx_out) {
    __shared__ float s_pd[TQ][NN];                 // 32 KiB
    __shared__ __align__(16) float s_q[CC][TQ];    // 1 KiB
    __shared__ int s_cand[TQ][NC];

    int tid = threadIdx.x;
    int b = blockIdx.x / (NN / TQ);
    int n0 = (blockIdx.x % (NN / TQ)) * TQ;
    const float* xb = x + (size_t)b * CC * NN;

    { int c = tid >> 2, q = tid & 3; s_q[c][q] = xb[c * NN + n0 + q]; }
    __syncthreads();

    float xxn[TQ];
#pragma unroll
    for (int q = 0; q < TQ; ++q) xxn[q] = xxf[b * NN + n0 + q];

    // ---- fp32 distance fill: thread owns 4 consecutive m, 2 groups ----
    for (int g = 0; g < 2; ++g) {
        int m = g * 1024 + tid * 4;
        float acc[4][TQ];
#pragma unroll
        for (int i = 0; i < 4; ++i)
#pragma unroll
            for (int q = 0; q < TQ; ++q) acc[i][q] = 0.f;

        for (int c = 0; c < CC; ++c) {
            float4 xv = *(const float4*)(xb + c * NN + m);
            float4 qv = *(const float4*)(&s_q[c][0]);
            float xs[4] = {xv.x, xv.y, xv.z, xv.w};
            float qs[4] = {qv.x, qv.y, qv.z, qv.w};
#pragma unroll
            for (int i = 0; i < 4; ++i)
#pragma unroll
                for (int q = 0; q < TQ; ++q) acc[i][q] += qs[q] * xs[i];
        }
        float4 xm4 = *(const float4*)(xxf + b * NN + m);
        float xms[4] = {xm4.x, xm4.y, xm4.z, xm4.w};
#pragma unroll
        for (int q = 0; q < TQ; ++q) {
            float4 pdv;
            pdv.x = (2.f * acc[0][q] - xxn[q]) - xms[0];
            pdv.y = (2.f * acc[1][q] - xxn[q]) - xms[1];
            pdv.z = (2.f * acc[2][q] - xxn[q]) - xms[2];
            pdv.w = (2.f * acc[3][q] - xxn[q]) - xms[3];
            *(float4*)(&s_pd[q][m]) = pdv;          // conflict-free b128 stores
        }
    }
    __syncthreads();

    // ---- fp32 top-26 selection: one wave per query, private pd row ----
    int q = tid >> 6;
    int lane = tid & 63;
    float* pd = s_pd[q];

    for (int t = 0; t < NC; ++t) {
        float best = -INFINITY;
        int bi = NN;
#pragma unroll
        for (int r = 0; r < NN / 64; ++r) {
            int m = lane + r * 64;
            float v = pd[m];
            if (v > best) { best = v; bi = m; }     // strict > keeps lowest m
        }
#pragma unroll
        for (int off = 32; off; off >>= 1) {
            float ov = __shfl_down(best, off);
            int oi = __shfl_down(bi, off);
            if (ov > best || (ov == best && oi < bi)) { best = ov; bi = oi; }
        }
        bi = __shfl(bi, 0);
        if (lane == 0) { s_cand[q][t] = bi; pd[bi] = -INFINITY; }
        // no barrier: this wave is the only reader/writer of its pd row
    }

    // ---- fp64 refine of the 26 candidates ----
    int nq = n0 + q;
    const float* xtb = xt + (size_t)b * NN * CC;
    double qd = (double)xtb[(size_t)nq * CC + lane];   // lane = channel
    double myv = 0.0;
    for (int t = 0; t < NC; ++t) {
        int cand = s_cand[q][t];
        double p = qd * (double)xtb[(size_t)cand * CC + lane];
#pragma unroll
        for (int off = 32; off; off >>= 1) p += __shfl_xor(p, off);
        if (lane == t) myv = p;                        // lane t keeps candidate t's dot
    }

    double val = -INFINITY;
    int idx = 0x7fffffff;
    double xxq = xxd[b * NN + nq];
    if (lane < NC) {
        int cand = s_cand[q][lane];
        val = 2.0 * myv - xxq - xxd[b * NN + cand];
        idx = cand;
    }

    // ---- bitonic sort, 32-lane groups, (val desc, idx asc) ----
#pragma unroll
    for (int k = 2; k <= 32; k <<= 1) {
#pragma unroll
        for (int j = k >> 1; j > 0; j >>= 1) {
            double ov = __shfl_xor(val, j, 32);
            int oi = __shfl_xor(idx, j, 32);
            bool lower = (lane & j) == 0;
            bool desc = (lane & k) == 0;
            bool better = (val > ov) || (val == ov && idx < oi);
            bool keep = (better == (lower == desc));
            if (!keep) { val = ov; idx = oi; }
        }
    }

    if (lane < KK) {
        size_t obase = ((size_t)b * NN + nq) * KK;
        idx_ws[obase + lane] = idx;
        idx_out[obase + lane] = (float)(idx + b * NN);
    }
}

// ---------------------------------------------------------------------------
// x1: mean of top-14 of 20 gathered neighbor values, written channel-major
// as x1t[b][c][n]. Computed as (sum20 - six minima)/14 (order-independent).
// Block = 256 thr handles 16 points.
// ---------------------------------------------------------------------------
__global__ __launch_bounds__(256) void x1_kernel(const float* __restrict__ xt,
                                                 const int* __restrict__ idx_ws,
                                                 float* __restrict__ x1t) {
    __shared__ int s_idx[16][KK];
    __shared__ float s_out[64][17];
    int tid = threadIdx.x;
    int b = blockIdx.x >> 7;                 // 128 tiles/batch
    int n0 = (blockIdx.x & 127) * 16;
    const float* xtb = xt + (size_t)b * NN * CC;

    for (int i = tid; i < 16 * KK; i += 256)
        s_idx[i / KK][i % KK] = idx_ws[((size_t)b * NN + n0) * KK + i];
    __syncthreads();

    int pl = tid >> 6, c = tid & 63;
#pragma unroll
    for (int it = 0; it < 4; ++it) {
        int nl = it * 4 + pl;
        float vals[KK];
        float sum = 0.f;
#pragma unroll
        for (int j = 0; j < KK; ++j) {
            vals[j] = xtb[(size_t)s_idx[nl][j] * CC + c];   // coalesced row read
            sum += vals[j];
        }
#pragma unroll
        for (int t = 0; t < KK - K2; ++t) {   // drop 6 smallest
            float worst = INFINITY;
            int wj = 0;
#pragma unroll
            for (int j = 0; j < KK; ++j)
                if (vals[j] < worst) { worst = vals[j]; wj = j; }
            sum -= worst;
            vals[wj] = INFINITY;
        }
        s_out[c][nl] = sum / (float)K2;
    }
    __syncthreads();

    int cw = tid >> 2, nw = (tid & 3) * 4;
    float4 v = make_float4(s_out[cw][nw], s_out[cw][nw + 1],
                           s_out[cw][nw + 2], s_out[cw][nw + 3]);
    *(float4*)(&x1t[((size_t)b * CC + cw) * NN + n0 + nw]) = v;
}

// ---------------------------------------------------------------------------
// feat: feature[b,ch,n,j]:
//   ch <  64: x1t[b,ch,idx[b,n,j]] - x[b,ch,n]   (gathers L1-resident: 8KB row)
//   ch >= 64: x[b,ch-64,n]
// ---------------------------------------------------------------------------
__global__ __launch_bounds__(256) void feat_kernel(const float* __restrict__ x,
                                                   const float* __restrict__ x1t,
                                                   const int* __restrict__ idx_ws,
                                                   float* __restrict__ out) {
    int bc = blockIdx.x;
    int b = bc >> 7, ch = bc & 127;
    const float* xb = x + (size_t)b * CC * NN;
    float* o = out + (size_t)bc * NN * KK;
    const int* idxb = idx_ws + (size_t)b * NN * KK;

    if (ch < CC) {
        const float* row = x1t + ((size_t)b * CC + ch) * NN;
        const float* xr = xb + ch * NN;
        for (int e = threadIdx.x; e < NN * KK; e += 256)
            o[e] = row[idxb[e]] - xr[e / KK];
    } else {
        const float* xr = xb + (ch - CC) * NN;
        for (int e = threadIdx.x; e < NN * KK; e += 256)
            o[e] = xr[e / KK];
    }
}

// ---------------------------------------------------------------------------
extern "C" void kernel_launch(void* const* d_in, const int* in_sizes, int n_in,
                              void* d_out, int out_size, void* d_ws, size_t ws_size,
                              hipStream_t stream) {
    const float* x = (const float*)d_in[0];   // (B, C, N) fp32
    float* out = (float*)d_out;

    // workspace layout (all 256B-aligned by construction)
    char* ws = (char*)d_ws;
    float* xt   = (float*)ws;                                   // B*N*C
    float* x1t  = (float*)(ws + (size_t)8388608);               // B*C*N
    double* xxd = (double*)(ws + (size_t)16777216);             // B*N
    float* xxf  = (float*)(ws + (size_t)17039360);              // B*N
    int* idx_ws = (int*)(ws + (size_t)17170432);                // B*N*K

    float* idx_out = out + (size_t)BB * 2 * CC * NN * KK;       // idx_flat tail

    prep_kernel<<<BB * (NN / 64), 256, 0, stream>>>(x, xt, xxf, xxd);
    knn_kernel<<<BB * (NN / TQ), 256, 0, stream>>>(x, xt, xxf, xxd, idx_ws, idx_out);
    x1_kernel<<<BB * (NN / 16), 256, 0, stream>>>(xt, idx_ws, x1t);
    feat_kernel<<<BB * 2 * CC, 256, 0, stream>>>(x, x1t, idx_ws, out);
}

// Round 4
// 660.040 us; speedup vs baseline: 2.1059x; 1.3808x over previous
//
#include <hip/hip_runtime.h>
#include <cstdint>
#include <cstddef>
#include <math.h>

// Problem constants (match reference: B,C,N,K = 16,64,2048,20)
#define BB 16
#define CC 64
#define NN 2048
#define KK 20
#define K2 14   // ceil(20*2/3)
#define TQ 8    // queries per block in knn kernel (one per wave)
#define NC 26   // fp32 candidate count (margin over K=20 for fp32->fp64 rank safety)

// ---------------------------------------------------------------------------
// prep: xt[b][n][c] = x[b][c][n]  (fp32, 256B rows), plus norms in fp64+fp32.
// ---------------------------------------------------------------------------
__global__ __launch_bounds__(256) void prep_kernel(const float* __restrict__ x,
                                                   float* __restrict__ xt,
                                                   float* __restrict__ xxf,
                                                   double* __restrict__ xxd) {
    __shared__ float s_t[64][65];
    int b = blockIdx.x >> 5;
    int n0 = (blockIdx.x & 31) * 64;
    const float* xb = x + (size_t)b * CC * NN;
    int tid = threadIdx.x;
    int cq = tid >> 6;
    int nl = tid & 63;

#pragma unroll
    for (int r = 0; r < 16; ++r) {
        int c = r * 4 + cq;
        s_t[c][nl] = xb[c * NN + n0 + nl];
    }
    __syncthreads();

#pragma unroll
    for (int r = 0; r < 16; ++r) {
        int n = r * 4 + cq;
        xt[((size_t)b * NN + n0 + n) * CC + nl] = s_t[nl][n];
    }

    if (tid < 64) {
        double s = 0.0;
#pragma unroll
        for (int c = 0; c < CC; ++c) {
            double v = (double)s_t[c][tid];
            s += v * v;
        }
        xxd[b * NN + n0 + tid] = s;
        xxf[b * NN + n0 + tid] = (float)s;
    }
}

// ---------------------------------------------------------------------------
// knn v4: 512 threads = 8 waves; 8 queries/block (one per wave).
// Phase 1: block-cooperative fp32 distance fill into LDS (8 rows).
// Phase 2: per-wave register-resident threshold selection:
//   lane holds 32 pd values; tau = 26th-largest lane-max (bitonic, values);
//   survivors (>= tau, provably >= 26 of them, ~32 expected) compacted to
//   LDS, bitonic-sorted (val desc, idx asc), top-26 taken. Exact iterative
//   fallback if survivors > 64 (pathological ties only).
// Phase 3: fp64 refine: candidate rows staged to (dead) pd LDS, lane t
//   computes candidate t's fp64 dot serially; 32-lane fp64 bitonic sort;
//   top-20 out.
// ---------------------------------------------------------------------------
__global__ __launch_bounds__(512) void knn_kernel(const float* __restrict__ x,
                                                  const float* __restrict__ xt,
                                                  const float* __restrict__ xxf,
                                                  const double* __restrict__ xxd,
                                                  int* __restrict__ idx_ws,
                                                  float* __restrict__ idx_out) {
    __shared__ float s_pd[TQ][NN];                 // 64 KiB
    __shared__ __align__(16) float s_q[CC][TQ];    // 2 KiB
    __shared__ float s_sv[TQ][64];                 // survivor values
    __shared__ int   s_si[TQ][64];                 // survivor indices

    int tid = threadIdx.x;
    int b = blockIdx.x >> 8;                       // NN/TQ = 256 blocks/batch
    int n0 = (blockIdx.x & 255) * TQ;
    const float* xb = x + (size_t)b * CC * NN;

    { int c = tid >> 3, qq = tid & 7; s_q[c][qq] = xb[c * NN + n0 + qq]; }
    __syncthreads();

    // ---- phase 1: fill (thread owns 4 consecutive m for all 8 queries) ----
    {
        float4 xa = *(const float4*)(xxf + b * NN + n0);
        float4 xc = *(const float4*)(xxf + b * NN + n0 + 4);
        float xxn[TQ] = {xa.x, xa.y, xa.z, xa.w, xc.x, xc.y, xc.z, xc.w};

        int m = tid * 4;
        float acc[TQ][4];
#pragma unroll
        for (int q = 0; q < TQ; ++q)
#pragma unroll
            for (int i = 0; i < 4; ++i) acc[q][i] = 0.f;

        for (int c = 0; c < CC; ++c) {
            float4 xv = *(const float4*)(xb + c * NN + m);
            float4 qa = *(const float4*)(&s_q[c][0]);
            float4 qb = *(const float4*)(&s_q[c][4]);
            float xs[4] = {xv.x, xv.y, xv.z, xv.w};
            float qs[TQ] = {qa.x, qa.y, qa.z, qa.w, qb.x, qb.y, qb.z, qb.w};
#pragma unroll
            for (int q = 0; q < TQ; ++q)
#pragma unroll
                for (int i = 0; i < 4; ++i) acc[q][i] += qs[q] * xs[i];
        }
        float4 xm4 = *(const float4*)(xxf + b * NN + m);
        float xms[4] = {xm4.x, xm4.y, xm4.z, xm4.w};
#pragma unroll
        for (int q = 0; q < TQ; ++q) {
            float4 pdv;
            pdv.x = (2.f * acc[q][0] - xxn[q]) - xms[0];
            pdv.y = (2.f * acc[q][1] - xxn[q]) - xms[1];
            pdv.z = (2.f * acc[q][2] - xxn[q]) - xms[2];
            pdv.w = (2.f * acc[q][3] - xxn[q]) - xms[3];
            *(float4*)(&s_pd[q][m]) = pdv;
        }
    }
    __syncthreads();

    // ---- phase 2: per-wave selection ----
    int q = tid >> 6;
    int lane = tid & 63;
    const float* pd = s_pd[q];

    float v[32];
#pragma unroll
    for (int r = 0; r < 32; ++r) v[r] = pd[lane + (r << 6)];   // idx = lane+64r

    float lmax = v[0]; int lr = 0;
#pragma unroll
    for (int r = 1; r < 32; ++r)
        if (v[r] > lmax) { lmax = v[r]; lr = r; }              // strict > : lowest idx

    // tau = 26th-largest lane-max (values-only 64-lane bitonic, descending)
    float sv = lmax;
#pragma unroll
    for (int k = 2; k <= 64; k <<= 1) {
#pragma unroll
        for (int j = k >> 1; j > 0; j >>= 1) {
            float o = __shfl_xor(sv, j);
            bool dird = ((lane & k) == 0);
            bool first = ((lane & j) == 0);
            sv = (first == dird) ? fmaxf(sv, o) : fminf(sv, o);
        }
    }
    float tau = __shfl(sv, 25);

    int cnt = 0;
#pragma unroll
    for (int r = 0; r < 32; ++r) cnt += (v[r] >= tau) ? 1 : 0;
    int incl = cnt;
#pragma unroll
    for (int off = 1; off < 64; off <<= 1) {
        int o = __shfl_up(incl, off);
        if (lane >= off) incl += o;
    }
    int S = __shfl(incl, 63);

    float fv = -INFINITY;
    int fi = 0x7fffffff;
    if (S <= 64) {
        int w = incl - cnt;
#pragma unroll
        for (int r = 0; r < 32; ++r) {
            if (v[r] >= tau) { s_sv[q][w] = v[r]; s_si[q][w] = lane + (r << 6); ++w; }
        }
        if (lane < S) { fv = s_sv[q][lane]; fi = s_si[q][lane]; }
    } else {
        // pathological (mass ties): exact iterative top-26 extraction
        for (int t = 0; t < NC; ++t) {
            float bv = lmax; int bi = lane + (lr << 6);
#pragma unroll
            for (int off = 32; off; off >>= 1) {
                float ov = __shfl_xor(bv, off);
                int oi = __shfl_xor(bi, off);
                if (ov > bv || (ov == bv && oi < bi)) { bv = ov; bi = oi; }
            }
            if (lane == t) { fv = bv; fi = bi; }
            if ((bi & 63) == lane) {
                int rsel = bi >> 6;
#pragma unroll
                for (int r = 0; r < 32; ++r) if (r == rsel) v[r] = -INFINITY;
                lmax = v[0]; lr = 0;
#pragma unroll
                for (int r = 1; r < 32; ++r)
                    if (v[r] > lmax) { lmax = v[r]; lr = r; }
            }
        }
    }

    // 64-lane bitonic sort of (fv desc, fi asc) -> lanes 0..25 = fp32 top-26
#pragma unroll
    for (int k = 2; k <= 64; k <<= 1) {
#pragma unroll
        for (int j = k >> 1; j > 0; j >>= 1) {
            float ov = __shfl_xor(fv, j);
            int oi = __shfl_xor(fi, j);
            bool dird = ((lane & k) == 0);
            bool first = ((lane & j) == 0);
            bool better = (fv > ov) || (fv == ov && fi < oi);
            if (better != (first == dird)) { fv = ov; fi = oi; }
        }
    }

    // ---- phase 3: fp64 refine ----
    float* s_c = (float*)&s_pd[q][0];              // reuse dead pd row, 64x27
    const float* xtb = xt + (size_t)b * NN * CC;
    int nq = n0 + q;

#pragma unroll
    for (int t = 0; t < NC; ++t) {
        int cand = __shfl(fi, t);
        s_c[lane * 27 + t] = xtb[(size_t)cand * CC + lane];   // coalesced row
    }

    double accd = 0.0;
    for (int c = 0; c < CC; ++c) {
        double qc = (double)s_q[c][q];                        // broadcast read
        double cd = (double)s_c[c * 27 + lane];               // conflict-free
        accd = fma(qc, cd, accd);
    }

    double val = -INFINITY;
    int idxq = 0x7fffffff;
    if (lane < NC) {
        val = 2.0 * accd - xxd[b * NN + nq] - xxd[b * NN + fi];
        idxq = fi;
    }

    // 32-lane fp64 bitonic (val desc, idx asc)
#pragma unroll
    for (int k = 2; k <= 32; k <<= 1) {
#pragma unroll
        for (int j = k >> 1; j > 0; j >>= 1) {
            double ov = __shfl_xor(val, j, 32);
            int oi = __shfl_xor(idxq, j, 32);
            bool dird = ((lane & k) == 0);
            bool first = ((lane & j) == 0);
            bool better = (val > ov) || (val == ov && idxq < oi);
            if (better != (first == dird)) { val = ov; idxq = oi; }
        }
    }

    if (lane < KK) {
        size_t obase = ((size_t)b * NN + nq) * KK;
        idx_ws[obase + lane] = idxq;
        idx_out[obase + lane] = (float)(idxq + b * NN);
    }
}

// ---------------------------------------------------------------------------
// x1: mean of top-14 of 20 gathered neighbor values, written channel-major
// as x1t[b][c][n]. (sum20 - six minima)/14, order-independent.
// ---------------------------------------------------------------------------
__global__ __launch_bounds__(256) void x1_kernel(const float* __restrict__ xt,
                                                 const int* __restrict__ idx_ws,
                                                 float* __restrict__ x1t) {
    __shared__ int s_idx[16][KK];
    __shared__ float s_out[64][17];
    int tid = threadIdx.x;
    int b = blockIdx.x >> 7;
    int n0 = (blockIdx.x & 127) * 16;
    const float* xtb = xt + (size_t)b * NN * CC;

    for (int i = tid; i < 16 * KK; i += 256)
        s_idx[i / KK][i % KK] = idx_ws[((size_t)b * NN + n0) * KK + i];
    __syncthreads();

    int pl = tid >> 6, c = tid & 63;
#pragma unroll
    for (int it = 0; it < 4; ++it) {
        int nl = it * 4 + pl;
        float vals[KK];
        float sum = 0.f;
#pragma unroll
        for (int j = 0; j < KK; ++j) {
            vals[j] = xtb[(size_t)s_idx[nl][j] * CC + c];
            sum += vals[j];
        }
#pragma unroll
        for (int t = 0; t < KK - K2; ++t) {
            float worst = INFINITY;
            int wj = 0;
#pragma unroll
            for (int j = 0; j < KK; ++j)
                if (vals[j] < worst) { worst = vals[j]; wj = j; }
            sum -= worst;
            vals[wj] = INFINITY;
        }
        s_out[c][nl] = sum / (float)K2;
    }
    __syncthreads();

    int cw = tid >> 2, nw = (tid & 3) * 4;
    float4 v = make_float4(s_out[cw][nw], s_out[cw][nw + 1],
                           s_out[cw][nw + 2], s_out[cw][nw + 3]);
    *(float4*)(&x1t[((size_t)b * CC + cw) * NN + n0 + nw]) = v;
}

// ---------------------------------------------------------------------------
// feat: float4-vectorized. feature[b,ch,n,j]:
//   ch <  64: x1t[b,ch,idx[b,n,j]] - x[b,ch,n]
//   ch >= 64: x[b,ch-64,n]
// ---------------------------------------------------------------------------
__global__ __launch_bounds__(256) void feat_kernel(const float* __restrict__ x,
                                                   const float* __restrict__ x1t,
                                                   const int* __restrict__ idx_ws,
                                                   float* __restrict__ out) {
    int bc = blockIdx.x;
    int b = bc >> 7, ch = bc & 127;
    const float* xb = x + (size_t)b * CC * NN;
    float* o = out + (size_t)bc * NN * KK;
    const int* idxb = idx_ws + (size_t)b * NN * KK;

    if (ch < CC) {
        const float* row = x1t + ((size_t)b * CC + ch) * NN;
        const float* xr = xb + ch * NN;
        for (int it = 0; it < 40; ++it) {
            unsigned e = (it * 256 + threadIdx.x) * 4;
            int4 id4 = *(const int4*)(idxb + e);
            float4 o4;
            o4.x = row[id4.x] - xr[(e    ) / KK];
            o4.y = row[id4.y] - xr[(e + 1) / KK];
            o4.z = row[id4.z] - xr[(e + 2) / KK];
            o4.w = row[id4.w] - xr[(e + 3) / KK];
            *(float4*)(o + e) = o4;
        }
    } else {
        const float* xr = xb + (ch - CC) * NN;
        for (int it = 0; it < 40; ++it) {
            unsigned e = (it * 256 + threadIdx.x) * 4;
            float4 o4;
            o4.x = xr[(e    ) / KK];
            o4.y = xr[(e + 1) / KK];
            o4.z = xr[(e + 2) / KK];
            o4.w = xr[(e + 3) / KK];
            *(float4*)(o + e) = o4;
        }
    }
}

// ---------------------------------------------------------------------------
extern "C" void kernel_launch(void* const* d_in, const int* in_sizes, int n_in,
                              void* d_out, int out_size, void* d_ws, size_t ws_size,
                              hipStream_t stream) {
    const float* x = (const float*)d_in[0];   // (B, C, N) fp32
    float* out = (float*)d_out;

    char* ws = (char*)d_ws;
    float* xt   = (float*)ws;                                   // B*N*C
    float* x1t  = (float*)(ws + (size_t)8388608);               // B*C*N
    double* xxd = (double*)(ws + (size_t)16777216);             // B*N
    float* xxf  = (float*)(ws + (size_t)17039360);              // B*N
    int* idx_ws = (int*)(ws + (size_t)17170432);                // B*N*K

    float* idx_out = out + (size_t)BB * 2 * CC * NN * KK;       // idx_flat tail

    prep_kernel<<<BB * (NN / 64), 256, 0, stream>>>(x, xt, xxf, xxd);
    knn_kernel<<<BB * (NN / TQ), 512, 0, stream>>>(x, xt, xxf, xxd, idx_ws, idx_out);
    x1_kernel<<<BB * (NN / 16), 256, 0, stream>>>(xt, idx_ws, x1t);
    feat_kernel<<<BB * 2 * CC, 256, 0, stream>>>(x, x1t, idx_ws, out);
}